// Round 1
// baseline (89.532 us; speedup 1.0000x reference)
//
#include <hip/hip_runtime.h>

#define N_NODES 4096
#define F_FEAT  64
#define FE_FEAT 16
#define H_HEADS 4
#define E_EDGES 65536

#define TBL_BITS 18
#define TBL_SIZE (1u << TBL_BITS)
#define TBL_MASK (TBL_SIZE - 1u)

// ---------------------------------------------------------------------------
// K1: node_proj = node_inputs @ Wn + bn   -> [4096, 256] row-major (flat)
// Indexed later as node_proj[h,d,f] = buf[h*N*F + d*F + f] (pure reshape).
// One block per node row; thread c computes output column c.
// ---------------------------------------------------------------------------
__global__ void k_node_gemm(const float* __restrict__ X,
                            const float* __restrict__ Wn,
                            const float* __restrict__ bn,
                            float* __restrict__ out) {
    __shared__ float xrow[F_FEAT];
    const int n = blockIdx.x;
    const int c = threadIdx.x;  // 0..255
    if (threadIdx.x < F_FEAT) xrow[threadIdx.x] = X[n * F_FEAT + threadIdx.x];
    __syncthreads();
    float acc = bn[c];
#pragma unroll 16
    for (int k = 0; k < F_FEAT; ++k)
        acc = fmaf(xrow[k], Wn[k * (F_FEAT * H_HEADS) + c], acc);
    out[n * (F_FEAT * H_HEADS) + c] = acc;
}

// ---------------------------------------------------------------------------
// K2: edge_proj = (edge_inputs @ We + be) * (1/sqrt(FE))  -> [65536, 4] flat.
// Indexed later as edge_proj[h,e] = buf[h*E + e] (pure reshape).
// One thread per edge; vectorized loads/stores.
// ---------------------------------------------------------------------------
__global__ void k_edge_gemm(const float* __restrict__ Xe,
                            const float* __restrict__ We,
                            const float* __restrict__ be,
                            float* __restrict__ out) {
    const int e = blockIdx.x * blockDim.x + threadIdx.x;
    if (e >= E_EDGES) return;
    const float4* xin = (const float4*)(Xe + (size_t)e * FE_FEAT);
    float x[FE_FEAT];
    float4 v0 = xin[0], v1 = xin[1], v2 = xin[2], v3 = xin[3];
    x[0]=v0.x; x[1]=v0.y; x[2]=v0.z; x[3]=v0.w;
    x[4]=v1.x; x[5]=v1.y; x[6]=v1.z; x[7]=v1.w;
    x[8]=v2.x; x[9]=v2.y; x[10]=v2.z; x[11]=v2.w;
    x[12]=v3.x; x[13]=v3.y; x[14]=v3.z; x[15]=v3.w;
    float a0 = be[0], a1 = be[1], a2 = be[2], a3 = be[3];
#pragma unroll
    for (int k = 0; k < FE_FEAT; ++k) {
        const float xv = x[k];
        a0 = fmaf(xv, We[k * H_HEADS + 0], a0);
        a1 = fmaf(xv, We[k * H_HEADS + 1], a1);
        a2 = fmaf(xv, We[k * H_HEADS + 2], a2);
        a3 = fmaf(xv, We[k * H_HEADS + 3], a3);
    }
    const float s = 0.25f;  // 1/sqrt(16)
    ((float4*)out)[e] = make_float4(a0 * s, a1 * s, a2 * s, a3 * s);
}

// ---------------------------------------------------------------------------
// K3: per-head softmax stats over the E axis. One block per head.
// stats[h] = max, stats[H+h] = 1/sum(exp(x-max)).
// ---------------------------------------------------------------------------
__global__ void k_softmax_stats(const float* __restrict__ ep,
                                float* __restrict__ stats) {
    const int h = blockIdx.x;
    const float* p = ep + (size_t)h * E_EDGES;  // contiguous span (flat view)
    __shared__ float red[1024];
    float m = -INFINITY;
    for (int i = threadIdx.x; i < E_EDGES; i += blockDim.x)
        m = fmaxf(m, p[i]);
    red[threadIdx.x] = m;
    __syncthreads();
    for (int s = blockDim.x / 2; s > 0; s >>= 1) {
        if (threadIdx.x < (unsigned)s)
            red[threadIdx.x] = fmaxf(red[threadIdx.x], red[threadIdx.x + s]);
        __syncthreads();
    }
    m = red[0];
    __syncthreads();
    float sum = 0.f;
    for (int i = threadIdx.x; i < E_EDGES; i += blockDim.x)
        sum += expf(p[i] - m);
    red[threadIdx.x] = sum;
    __syncthreads();
    for (int s = blockDim.x / 2; s > 0; s >>= 1) {
        if (threadIdx.x < (unsigned)s)
            red[threadIdx.x] += red[threadIdx.x + s];
        __syncthreads();
    }
    if (threadIdx.x == 0) {
        stats[h] = m;
        stats[H_HEADS + h] = 1.0f / red[0];
    }
}

// ---------------------------------------------------------------------------
// K4: dedup winner table. key = src*4096 + dst. Last-occurring edge index
// wins (matches numpy fancy-assignment semantics for duplicate indices).
// Open-addressing hash; entry = (key+1)<<24 | e; winner per key = max e.
// ---------------------------------------------------------------------------
__device__ __forceinline__ unsigned hash_key(unsigned key) {
    return (key * 2654435761u) >> (32 - TBL_BITS);
}

__global__ void k_hash_insert(const int* __restrict__ src,
                              const int* __restrict__ dst,
                              unsigned long long* __restrict__ tbl) {
    const int e = blockIdx.x * blockDim.x + threadIdx.x;
    if (e >= E_EDGES) return;
    const unsigned key = ((unsigned)src[e] << 12) | (unsigned)dst[e];
    const unsigned long long tag = (unsigned long long)(key + 1u);
    const unsigned long long pack = (tag << 24) | (unsigned long long)e;
    unsigned i = hash_key(key);
    while (true) {
        unsigned long long cur = tbl[i];
        if (cur == 0ull) {
            unsigned long long old = atomicCAS(&tbl[i], 0ull, pack);
            if (old == 0ull) return;
            cur = old;
        }
        if ((cur >> 24) == tag) {
            atomicMax(&tbl[i], pack);
            return;
        }
        i = (i + 1u) & TBL_MASK;
    }
}

// ---------------------------------------------------------------------------
// K5: message passing + head mean.
// One wave (64 lanes) per edge; lane = feature f. For winning edges:
//   out[src, f] += 0.25 * sum_h attn[h,e] * node_proj[h, dst, f]
// node_proj reads are 256B-contiguous per wave (coalesced).
// ---------------------------------------------------------------------------
__global__ void k_message(const float* __restrict__ nproj,
                          const float* __restrict__ ep,
                          const float* __restrict__ stats,
                          const int* __restrict__ src,
                          const int* __restrict__ dst,
                          const unsigned long long* __restrict__ tbl,
                          float* __restrict__ out) {
    const int e = blockIdx.x * (blockDim.x >> 6) + (threadIdx.x >> 6);
    const int f = threadIdx.x & 63;
    if (e >= E_EDGES) return;
    const int s = src[e];
    const int d = dst[e];
    const unsigned key = ((unsigned)s << 12) | (unsigned)d;
    const unsigned long long tag = (unsigned long long)(key + 1u);
    unsigned i = hash_key(key);
    unsigned long long cur;
    while (true) {
        cur = tbl[i];
        if ((cur >> 24) == tag) break;
        i = (i + 1u) & TBL_MASK;
    }
    if ((unsigned)(cur & 0xFFFFFFull) != (unsigned)e) return;  // duplicate loser

    float val = 0.f;
#pragma unroll
    for (int h = 0; h < H_HEADS; ++h) {
        const float a = expf(ep[h * E_EDGES + e] - stats[h]) * stats[H_HEADS + h];
        val = fmaf(a, nproj[(size_t)h * (N_NODES * F_FEAT) + d * F_FEAT + f], val);
    }
    atomicAdd(&out[s * F_FEAT + f], 0.25f * val);
}

// ---------------------------------------------------------------------------
extern "C" void kernel_launch(void* const* d_in, const int* in_sizes, int n_in,
                              void* d_out, int out_size, void* d_ws, size_t ws_size,
                              hipStream_t stream) {
    const float* node_inputs = (const float*)d_in[0];
    const float* edge_inputs = (const float*)d_in[1];
    const int*   src         = (const int*)d_in[2];
    const int*   dst         = (const int*)d_in[3];
    const float* Wn          = (const float*)d_in[4];
    const float* bn          = (const float*)d_in[5];
    const float* We          = (const float*)d_in[6];
    const float* be          = (const float*)d_in[7];
    float* out = (float*)d_out;

    char* ws = (char*)d_ws;
    float* nproj = (float*)ws;                                        // 4 MB
    float* ep    = (float*)(ws + (size_t)N_NODES * 256 * 4);          // 1 MB
    float* stats = (float*)(ws + 5u * 1024u * 1024u);                 // 32 B
    unsigned long long* tbl =
        (unsigned long long*)(ws + 5u * 1024u * 1024u + 256u);        // 2 MB

    // Harness poisons once with 0xAA and never re-poisons: zero every call.
    hipMemsetAsync(out, 0, (size_t)N_NODES * F_FEAT * sizeof(float), stream);
    hipMemsetAsync(tbl, 0, (size_t)TBL_SIZE * sizeof(unsigned long long), stream);

    k_node_gemm<<<N_NODES, 256, 0, stream>>>(node_inputs, Wn, bn, nproj);
    k_edge_gemm<<<E_EDGES / 256, 256, 0, stream>>>(edge_inputs, We, be, ep);
    k_softmax_stats<<<H_HEADS, 1024, 0, stream>>>(ep, stats);
    k_hash_insert<<<E_EDGES / 256, 256, 0, stream>>>(src, dst, tbl);
    k_message<<<E_EDGES / 4, 256, 0, stream>>>(nproj, ep, stats, src, dst, tbl, out);
}

// Round 2
// 86.211 us; speedup vs baseline: 1.0385x; 1.0385x over previous
//
#include <hip/hip_runtime.h>

#define N_NODES 4096
#define F_FEAT  64
#define FE_FEAT 16
#define H_HEADS 4
#define E_EDGES 65536

#define TBL_BITS 18
#define TBL_SIZE (1u << TBL_BITS)
#define TBL_MASK (TBL_SIZE - 1u)

// ---------------------------------------------------------------------------
// K0: zero d_out (1 MB) and the hash table (2 MB) in one launch.
// (hipMemsetAsync -> rocclr fillBuffer ran at ~42 us per call; this is ~2 us.)
// out: 262144 floats = 65536 float4 ; tbl: 262144 u64 = 131072 float4.
// ---------------------------------------------------------------------------
__global__ void k_zero(float4* __restrict__ out4, float4* __restrict__ tbl4) {
    const int i = blockIdx.x * blockDim.x + threadIdx.x;
    const float4 z = make_float4(0.f, 0.f, 0.f, 0.f);
    if (i < 65536) out4[i] = z;
    else           tbl4[i - 65536] = z;
}

// ---------------------------------------------------------------------------
// K1: node_proj = node_inputs @ Wn + bn   -> [4096, 256] row-major (flat)
// Indexed later as node_proj[h,d,f] = buf[h*N*F + d*F + f] (pure reshape).
// One block per node row; thread c computes output column c.
// ---------------------------------------------------------------------------
__global__ void k_node_gemm(const float* __restrict__ X,
                            const float* __restrict__ Wn,
                            const float* __restrict__ bn,
                            float* __restrict__ out) {
    __shared__ float xrow[F_FEAT];
    const int n = blockIdx.x;
    const int c = threadIdx.x;  // 0..255
    if (threadIdx.x < F_FEAT) xrow[threadIdx.x] = X[n * F_FEAT + threadIdx.x];
    __syncthreads();
    float acc = bn[c];
#pragma unroll 16
    for (int k = 0; k < F_FEAT; ++k)
        acc = fmaf(xrow[k], Wn[k * (F_FEAT * H_HEADS) + c], acc);
    out[n * (F_FEAT * H_HEADS) + c] = acc;
}

// ---------------------------------------------------------------------------
// K2: edge_proj = (edge_inputs @ We + be) * (1/sqrt(FE))  -> [65536, 4] flat.
// Indexed later as edge_proj[h,e] = buf[h*E + e] (pure reshape).
// One thread per edge; vectorized loads/stores.
// ---------------------------------------------------------------------------
__global__ void k_edge_gemm(const float* __restrict__ Xe,
                            const float* __restrict__ We,
                            const float* __restrict__ be,
                            float* __restrict__ out) {
    const int e = blockIdx.x * blockDim.x + threadIdx.x;
    if (e >= E_EDGES) return;
    const float4* xin = (const float4*)(Xe + (size_t)e * FE_FEAT);
    float x[FE_FEAT];
    float4 v0 = xin[0], v1 = xin[1], v2 = xin[2], v3 = xin[3];
    x[0]=v0.x; x[1]=v0.y; x[2]=v0.z; x[3]=v0.w;
    x[4]=v1.x; x[5]=v1.y; x[6]=v1.z; x[7]=v1.w;
    x[8]=v2.x; x[9]=v2.y; x[10]=v2.z; x[11]=v2.w;
    x[12]=v3.x; x[13]=v3.y; x[14]=v3.z; x[15]=v3.w;
    float a0 = be[0], a1 = be[1], a2 = be[2], a3 = be[3];
#pragma unroll
    for (int k = 0; k < FE_FEAT; ++k) {
        const float xv = x[k];
        a0 = fmaf(xv, We[k * H_HEADS + 0], a0);
        a1 = fmaf(xv, We[k * H_HEADS + 1], a1);
        a2 = fmaf(xv, We[k * H_HEADS + 2], a2);
        a3 = fmaf(xv, We[k * H_HEADS + 3], a3);
    }
    const float s = 0.25f;  // 1/sqrt(16)
    ((float4*)out)[e] = make_float4(a0 * s, a1 * s, a2 * s, a3 * s);
}

// ---------------------------------------------------------------------------
// K3: per-head softmax stats over the E axis. One block per head.
// stats[h] = max, stats[H+h] = 1/sum(exp(x-max)).
// ---------------------------------------------------------------------------
__global__ void k_softmax_stats(const float* __restrict__ ep,
                                float* __restrict__ stats) {
    const int h = blockIdx.x;
    const float* p = ep + (size_t)h * E_EDGES;  // contiguous span (flat view)
    __shared__ float red[1024];
    float m = -INFINITY;
    for (int i = threadIdx.x; i < E_EDGES; i += blockDim.x)
        m = fmaxf(m, p[i]);
    red[threadIdx.x] = m;
    __syncthreads();
    for (int s = blockDim.x / 2; s > 0; s >>= 1) {
        if (threadIdx.x < (unsigned)s)
            red[threadIdx.x] = fmaxf(red[threadIdx.x], red[threadIdx.x + s]);
        __syncthreads();
    }
    m = red[0];
    __syncthreads();
    float sum = 0.f;
    for (int i = threadIdx.x; i < E_EDGES; i += blockDim.x)
        sum += expf(p[i] - m);
    red[threadIdx.x] = sum;
    __syncthreads();
    for (int s = blockDim.x / 2; s > 0; s >>= 1) {
        if (threadIdx.x < (unsigned)s)
            red[threadIdx.x] += red[threadIdx.x + s];
        __syncthreads();
    }
    if (threadIdx.x == 0) {
        stats[h] = m;
        stats[H_HEADS + h] = 1.0f / red[0];
    }
}

// ---------------------------------------------------------------------------
// K4: dedup winner table. key = src*4096 + dst. Last-occurring edge index
// wins (matches numpy fancy-assignment semantics for duplicate indices).
// Open-addressing hash; entry = (key+1)<<24 | e; winner per key = max e.
// ---------------------------------------------------------------------------
__device__ __forceinline__ unsigned hash_key(unsigned key) {
    return (key * 2654435761u) >> (32 - TBL_BITS);
}

__global__ void k_hash_insert(const int* __restrict__ src,
                              const int* __restrict__ dst,
                              unsigned long long* __restrict__ tbl) {
    const int e = blockIdx.x * blockDim.x + threadIdx.x;
    if (e >= E_EDGES) return;
    const unsigned key = ((unsigned)src[e] << 12) | (unsigned)dst[e];
    const unsigned long long tag = (unsigned long long)(key + 1u);
    const unsigned long long pack = (tag << 24) | (unsigned long long)e;
    unsigned i = hash_key(key);
    while (true) {
        unsigned long long cur = tbl[i];
        if (cur == 0ull) {
            unsigned long long old = atomicCAS(&tbl[i], 0ull, pack);
            if (old == 0ull) return;
            cur = old;
        }
        if ((cur >> 24) == tag) {
            atomicMax(&tbl[i], pack);
            return;
        }
        i = (i + 1u) & TBL_MASK;
    }
}

// ---------------------------------------------------------------------------
// K5: message passing + head mean.
// One wave (64 lanes) per edge; lane = feature f. For winning edges:
//   out[src, f] += 0.25 * sum_h attn[h,e] * node_proj[h, dst, f]
// node_proj reads are 256B-contiguous per wave (coalesced).
// ---------------------------------------------------------------------------
__global__ void k_message(const float* __restrict__ nproj,
                          const float* __restrict__ ep,
                          const float* __restrict__ stats,
                          const int* __restrict__ src,
                          const int* __restrict__ dst,
                          const unsigned long long* __restrict__ tbl,
                          float* __restrict__ out) {
    const int e = blockIdx.x * (blockDim.x >> 6) + (threadIdx.x >> 6);
    const int f = threadIdx.x & 63;
    if (e >= E_EDGES) return;
    const int s = src[e];
    const int d = dst[e];
    const unsigned key = ((unsigned)s << 12) | (unsigned)d;
    const unsigned long long tag = (unsigned long long)(key + 1u);
    unsigned i = hash_key(key);
    unsigned long long cur;
    while (true) {
        cur = tbl[i];
        if ((cur >> 24) == tag) break;
        i = (i + 1u) & TBL_MASK;
    }
    if ((unsigned)(cur & 0xFFFFFFull) != (unsigned)e) return;  // duplicate loser

    float val = 0.f;
#pragma unroll
    for (int h = 0; h < H_HEADS; ++h) {
        const float a = expf(ep[h * E_EDGES + e] - stats[h]) * stats[H_HEADS + h];
        val = fmaf(a, nproj[(size_t)h * (N_NODES * F_FEAT) + d * F_FEAT + f], val);
    }
    atomicAdd(&out[s * F_FEAT + f], 0.25f * val);
}

// ---------------------------------------------------------------------------
extern "C" void kernel_launch(void* const* d_in, const int* in_sizes, int n_in,
                              void* d_out, int out_size, void* d_ws, size_t ws_size,
                              hipStream_t stream) {
    const float* node_inputs = (const float*)d_in[0];
    const float* edge_inputs = (const float*)d_in[1];
    const int*   src         = (const int*)d_in[2];
    const int*   dst         = (const int*)d_in[3];
    const float* Wn          = (const float*)d_in[4];
    const float* bn          = (const float*)d_in[5];
    const float* We          = (const float*)d_in[6];
    const float* be          = (const float*)d_in[7];
    float* out = (float*)d_out;

    char* ws = (char*)d_ws;
    float* nproj = (float*)ws;                                        // 4 MB
    float* ep    = (float*)(ws + (size_t)N_NODES * 256 * 4);          // 1 MB
    float* stats = (float*)(ws + 5u * 1024u * 1024u);                 // 32 B
    unsigned long long* tbl =
        (unsigned long long*)(ws + 5u * 1024u * 1024u + 256u);        // 2 MB

    // Custom zero (harness poisons 0xAA once, never re-poisons):
    // 65536 float4 for out + 131072 float4 for tbl = 196608 threads.
    k_zero<<<196608 / 256, 256, 0, stream>>>((float4*)out, (float4*)tbl);

    k_node_gemm<<<N_NODES, 256, 0, stream>>>(node_inputs, Wn, bn, nproj);
    k_edge_gemm<<<E_EDGES / 256, 256, 0, stream>>>(edge_inputs, We, be, ep);
    k_softmax_stats<<<H_HEADS, 1024, 0, stream>>>(ep, stats);
    k_hash_insert<<<E_EDGES / 256, 256, 0, stream>>>(src, dst, tbl);
    k_message<<<E_EDGES / 4, 256, 0, stream>>>(nproj, ep, stats, src, dst, tbl, out);
}

// Round 5
// 60.786 us; speedup vs baseline: 1.4729x; 1.4183x over previous
//
#include <hip/hip_runtime.h>

#define TBL_BITS 18
#define TBL_SIZE (1u << TBL_BITS)
#define TBL_MASK (TBL_SIZE - 1u)

// Grid geometry (fixed; phase indexing depends on it).
// 1024 blocks x 256 thr = 262144 threads = 4096 waves.
#define GBLK 1024
#define BLK  256

// RESHAPE SEMANTICS (the R3/R4 bug): reference does
//   edge_proj = (Xe @ We + be).reshape(H, E)   on a row-major [E,4] buffer
// so edge_proj[h,e] = flat[h*65536 + e]  (axis-scrambled!). Softmax group h
// is flat range [h*65536,(h+1)*65536) = matrix rows [h*16384,(h+1)*16384) x
// ALL 4 columns. We therefore always index the flat buffer directly.
// Same for node_proj[h,d,f] = npflat[h*262144 + d*64 + f].

struct Args {
    const float* X;  const float* Xe;
    const int* src;  const int* dst;
    const float* Wn; const float* bn;
    const float* We; const float* be;
    float* out;
    float* nproj;        // [4096*256] flat
    float* ep;           // [65536*4] flat, PRE-EXPONENTIATED matrix elements
    float* partials;     // [1024] per-wave scalar exp-sums (wave w -> group w>>8)
    float* stats;        // [4] = 0.25 / sum_h
    unsigned long long* tbl;  // [TBL_SIZE] dedup hash
};

__device__ __forceinline__ unsigned hash_key(unsigned key) {
    return (key * 2654435761u) >> (32 - TBL_BITS);
}

// ---------------------------------------------------------------------------
// K0: zero out+tbl; node GEMM (4 rows/thread, Wn column reused 4x);
//     edge GEMM -> exp (no max-sub: |logit*0.25| <= ~1.3, shift-invariant)
//     + per-wave scalar sums in FLAT order (group h = wave>>8).
// ---------------------------------------------------------------------------
__global__ __launch_bounds__(BLK, 4) void k_p0(Args A) {
    const int tid = blockIdx.x * BLK + threadIdx.x;
    {   // zero d_out (65536 f4) + hash table (131072 f4)
        const float4 z = make_float4(0.f, 0.f, 0.f, 0.f);
        if (tid < 65536)       ((float4*)A.out)[tid] = z;
        else if (tid < 196608) ((float4*)A.tbl)[tid - 65536] = z;
    }
    {   // node GEMM: thread -> column c, rows n0, n0+1024, n0+2048, n0+3072
        const int c  = tid & 255;
        const int n0 = tid >> 8;  // == blockIdx.x, wave-uniform
        const float b = A.bn[c];
        float a0 = b, a1 = b, a2 = b, a3 = b;
        const float* Wc = A.Wn + c;
#pragma unroll 8
        for (int k = 0; k < 64; ++k) {
            const float w = Wc[k * 256];
            a0 = fmaf(A.X[(n0       ) * 64 + k], w, a0);
            a1 = fmaf(A.X[(n0 + 1024) * 64 + k], w, a1);
            a2 = fmaf(A.X[(n0 + 2048) * 64 + k], w, a2);
            a3 = fmaf(A.X[(n0 + 3072) * 64 + k], w, a3);
        }
        A.nproj[(n0       ) * 256 + c] = a0;
        A.nproj[(n0 + 1024) * 256 + c] = a1;
        A.nproj[(n0 + 2048) * 256 + c] = a2;
        A.nproj[(n0 + 3072) * 256 + c] = a3;
    }
    if (tid < 65536) {  // edge GEMM row `tid` + exp + per-wave flat-order sum
        const float4* xi = (const float4*)(A.Xe + (size_t)tid * 16);
        float x[16];
        float4 v;
        v = xi[0]; x[0]=v.x;  x[1]=v.y;  x[2]=v.z;  x[3]=v.w;
        v = xi[1]; x[4]=v.x;  x[5]=v.y;  x[6]=v.z;  x[7]=v.w;
        v = xi[2]; x[8]=v.x;  x[9]=v.y;  x[10]=v.z; x[11]=v.w;
        v = xi[3]; x[12]=v.x; x[13]=v.y; x[14]=v.z; x[15]=v.w;
        float a0 = A.be[0], a1 = A.be[1], a2 = A.be[2], a3 = A.be[3];
#pragma unroll
        for (int k = 0; k < 16; ++k) {
            a0 = fmaf(x[k], A.We[k * 4 + 0], a0);
            a1 = fmaf(x[k], A.We[k * 4 + 1], a1);
            a2 = fmaf(x[k], A.We[k * 4 + 2], a2);
            a3 = fmaf(x[k], A.We[k * 4 + 3], a3);
        }
        const float e0 = expf(a0 * 0.25f), e1 = expf(a1 * 0.25f);
        const float e2 = expf(a2 * 0.25f), e3 = expf(a3 * 0.25f);
        ((float4*)A.ep)[tid] = make_float4(e0, e1, e2, e3);
        // Wave w covers matrix rows [64w,64w+64) = flat [256w,256w+256),
        // entirely inside softmax group h = w>>8 (16384 rows/group, 64|16384).
        float s = e0 + e1 + e2 + e3;
#pragma unroll
        for (int off = 32; off > 0; off >>= 1) s += __shfl_xor(s, off);
        if ((tid & 63) == 0) A.partials[tid >> 6] = s;
    }
}

// ---------------------------------------------------------------------------
// K1: hash-insert (last-occurring edge wins via atomicMax on packed (tag,e));
//     block 0 reduces partials: stats[h] = 0.25 / sum(partials[256h..256h+256)).
// ---------------------------------------------------------------------------
__global__ __launch_bounds__(BLK, 4) void k_p1(Args A) {
    const int tid = blockIdx.x * BLK + threadIdx.x;
    if (tid < 65536) {
        const unsigned key = ((unsigned)A.src[tid] << 12) | (unsigned)A.dst[tid];
        const unsigned long long tag  = (unsigned long long)(key + 1u);
        const unsigned long long pack = (tag << 24) | (unsigned long long)tid;
        unsigned i = hash_key(key);
        while (true) {
            unsigned long long cur = A.tbl[i];
            if (cur == 0ull) {
                unsigned long long old = atomicCAS(&A.tbl[i], 0ull, pack);
                if (old == 0ull) break;
                cur = old;
            }
            if ((cur >> 24) == tag) {
                atomicMax(&A.tbl[i], pack);
                break;
            }
            i = (i + 1u) & TBL_MASK;
        }
    }
    if (blockIdx.x == 0) {
        __shared__ float4 red[256];
        const int t = threadIdx.x;
        // component h = partials[h*256 + t]; tree-reduce over t.
        red[t] = make_float4(A.partials[t], A.partials[256 + t],
                             A.partials[512 + t], A.partials[768 + t]);
        __syncthreads();
        for (int s = 128; s > 0; s >>= 1) {
            if (t < s) {
                red[t].x += red[t + s].x; red[t].y += red[t + s].y;
                red[t].z += red[t + s].z; red[t].w += red[t + s].w;
            }
            __syncthreads();
        }
        if (t == 0) {
            A.stats[0] = 0.25f / red[0].x;  // fold head-mean 1/4 into 1/sum
            A.stats[1] = 0.25f / red[0].y;
            A.stats[2] = 0.25f / red[0].z;
            A.stats[3] = 0.25f / red[0].w;
        }
    }
}

// ---------------------------------------------------------------------------
// K2: message passing. Wave per edge (lane = feature), 16 edges per wave.
// attn[h,e] = ep_flat[h*65536 + e] * stats[h]   (flat reshape semantics!)
// out[s,f] += sum_h attn[h,e] * npflat[h*262144 + d*64 + f]  (winner only)
// ---------------------------------------------------------------------------
__global__ __launch_bounds__(BLK, 4) void k_p2(Args A) {
    const int tid = blockIdx.x * BLK + threadIdx.x;
    const int w = tid >> 6;   // 0..4095
    const int f = tid & 63;
    const float r0 = A.stats[0], r1 = A.stats[1];
    const float r2 = A.stats[2], r3 = A.stats[3];
    for (int i = 0; i < 16; ++i) {
        const int e = w * 16 + i;
        const int s = A.src[e], d = A.dst[e];
        const unsigned key = ((unsigned)s << 12) | (unsigned)d;
        const unsigned long long tag = (unsigned long long)(key + 1u);
        unsigned idx = hash_key(key);
        unsigned long long cur;
        while (true) {
            cur = A.tbl[idx];
            if ((cur >> 24) == tag) break;
            idx = (idx + 1u) & TBL_MASK;
        }
        if ((unsigned)(cur & 0xFFFFFFull) != (unsigned)e) continue;  // dup loser
        // Wave-uniform scalar loads (broadcast), flat-layout indexing.
        const float a0 = A.ep[e];
        const float a1 = A.ep[65536 + e];
        const float a2 = A.ep[131072 + e];
        const float a3 = A.ep[196608 + e];
        const int base = d * 64 + f;
        float v = a0 * r0 * A.nproj[base];
        v = fmaf(a1 * r1, A.nproj[base + 262144], v);
        v = fmaf(a2 * r2, A.nproj[base + 524288], v);
        v = fmaf(a3 * r3, A.nproj[base + 786432], v);
        atomicAdd(&A.out[s * 64 + f], v);
    }
}

// ---------------------------------------------------------------------------
extern "C" void kernel_launch(void* const* d_in, const int* in_sizes, int n_in,
                              void* d_out, int out_size, void* d_ws, size_t ws_size,
                              hipStream_t stream) {
    Args A;
    A.X   = (const float*)d_in[0];
    A.Xe  = (const float*)d_in[1];
    A.src = (const int*)d_in[2];
    A.dst = (const int*)d_in[3];
    A.Wn  = (const float*)d_in[4];
    A.bn  = (const float*)d_in[5];
    A.We  = (const float*)d_in[6];
    A.be  = (const float*)d_in[7];
    A.out = (float*)d_out;
    char* ws     = (char*)d_ws;
    A.nproj      = (float*)ws;                                     // 4 MB
    A.ep         = (float*)(ws + 4u * 1024u * 1024u);              // 1 MB
    A.partials   = (float*)(ws + 5u * 1024u * 1024u);              // 4 KB
    A.stats      = (float*)(ws + 5u * 1024u * 1024u + 16384u);     // 16 B
    A.tbl        = (unsigned long long*)(ws + 6u * 1024u * 1024u); // 2 MB

    k_p0<<<GBLK, BLK, 0, stream>>>(A);
    k_p1<<<GBLK, BLK, 0, stream>>>(A);
    k_p2<<<GBLK, BLK, 0, stream>>>(A);
}